// Round 1
// baseline (274.256 us; speedup 1.0000x reference)
//
#include <hip/hip_runtime.h>

#define OUT_COLS 448
#define OUT_STRIDE (OUT_COLS * 32)   // 14336 floats per batch row
#define NTREES 128
#define TDEPTH 6
#define NT (NTREES * TDEPTH)         // 768 rows
#define DD 32
#define BB 64
#define MAXJ 320

// ---------------------------------------------------------------- copy x into out[:, 0:64, :]
__global__ void copy_x_kernel(const float* __restrict__ x, float* __restrict__ out) {
    int idx = blockIdx.x * blockDim.x + threadIdx.x;
    if (idx < BB * 64 * DD) {
        int b = idx >> 11;        // / (64*32)
        int r = idx & 2047;
        out[(size_t)b * OUT_STRIDE + r] = x[idx];
    }
}

// ---------------------------------------------------------------- sparsemax over fsl rows, compacted
// One block per (n,t) row of length J. Exact rank-counting sparsemax (O(J^2), tiny).
__global__ void fs_kernel(const float* __restrict__ fsl, int J,
                          int* __restrict__ fj, float* __restrict__ fv,
                          int* __restrict__ fcnt) {
    int row = blockIdx.x;
    int tid = threadIdx.x;
    __shared__ float z[MAXJ];
    __shared__ int scount;
    __shared__ float ssum;
    __shared__ int offs[257];
    const float* zr = fsl + (size_t)row * J;
    for (int i = tid; i < J; i += 256) z[i] = zr[i];
    if (tid == 0) scount = 0;
    __syncthreads();

    int i0 = tid, i1 = tid + 256;
    bool h0 = i0 < J, h1 = i1 < J;
    float z0 = h0 ? z[i0] : 0.f;
    float z1 = h1 ? z[i1] : 0.f;
    int c0 = 0, c1 = 0;
    float s0 = 0.f, s1 = 0.f;
    for (int jj = 0; jj < J; ++jj) {
        float zj = z[jj];
        if (zj > z0 || (zj == z0 && jj <= i0)) { c0++; s0 += zj; }
        if (zj > z1 || (zj == z1 && jj <= i1)) { c1++; s1 += zj; }
    }
    // support condition at this element's (unique) descending rank
    bool cd0 = h0 && ((float)c0 * z0 > s0 - 1.0f);
    bool cd1 = h1 && ((float)c1 * z1 > s1 - 1.0f);
    int loc = (cd0 ? 1 : 0) + (cd1 ? 1 : 0);
    if (loc) atomicAdd(&scount, loc);
    __syncthreads();
    int ks = scount;                       // k_sup = count of satisfied (matches jnp.sum(support))
    if (h0 && c0 == ks) ssum = s0;         // exactly one element has rank == ks
    if (h1 && c1 == ks) ssum = s1;
    __syncthreads();
    float tau = (ssum - 1.0f) / (float)ks;
    float f0 = h0 ? fmaxf(z0 - tau, 0.f) : 0.f;
    float f1 = h1 ? fmaxf(z1 - tau, 0.f) : 0.f;

    // deterministic block-wide compaction of nonzeros
    int my = (f0 > 0.f ? 1 : 0) + (f1 > 0.f ? 1 : 0);
    offs[tid + 1] = my;
    __syncthreads();
    if (tid == 0) {
        offs[0] = 0;
        for (int i = 1; i <= 256; ++i) offs[i] += offs[i - 1];
    }
    __syncthreads();
    int p = offs[tid];
    size_t base = (size_t)row * J;
    if (f0 > 0.f) { fj[base + p] = i0; fv[base + p] = f0; p++; }
    if (f1 > 0.f) { fj[base + p] = i1; fv[base + p] = f1; }
    if (tid == 0) fcnt[row] = offs[256];
}

// ---------------------------------------------------------------- es_sum[n,t,d] = sum_j sparsemax(esl[n,t,j,:])[d]
// One block per (n,t); 8 lane-groups of 32 handle 8 j-rows per pass.
__global__ void es_kernel(const float* __restrict__ esl, int J,
                          float* __restrict__ es_sum) {
    int row = blockIdx.x;
    int tid = threadIdx.x;
    int lg = tid & 31;       // lane within 32-group (= d)
    int grp = tid >> 5;      // 0..7
    float acc = 0.f;
    for (int j0 = 0; j0 < J; j0 += 8) {
        int j = j0 + grp;
        const float* zr = esl + ((size_t)row * J + j) * 32;
        float z = zr[lg];
        float v = z;
        // bitonic sort DESCENDING across the 32-lane group
        #pragma unroll
        for (int k = 2; k <= 32; k <<= 1) {
            #pragma unroll
            for (int jm = k >> 1; jm > 0; jm >>= 1) {
                float o = __shfl_xor(v, jm);
                bool lower = (lg & jm) == 0;
                bool asc = (lg & k) != 0;      // flipped -> overall descending
                v = (lower == asc) ? fminf(v, o) : fmaxf(v, o);
            }
        }
        // inclusive prefix sum within the 32-lane group
        float cum = v;
        #pragma unroll
        for (int off = 1; off < 32; off <<= 1) {
            float o = __shfl_up(cum, off, 32);
            if (lg >= off) cum += o;
        }
        bool sup = ((float)(lg + 1) * v > cum - 1.0f);
        unsigned long long m = __ballot(sup);
        unsigned mh = (tid & 32) ? (unsigned)(m >> 32) : (unsigned)(m & 0xffffffffu);
        int ks = __popc(mh);
        float tsum = __shfl(cum, ks - 1, 32);
        float tau = (tsum - 1.0f) / (float)ks;
        acc += fmaxf(z - tau, 0.0f);
    }
    __shared__ float red[8][DD];
    red[grp][lg] = acc;
    __syncthreads();
    if (tid < 32) {
        float s = 0.f;
        #pragma unroll
        for (int g = 0; g < 8; ++g) s += red[g][tid];
        es_sum[(size_t)row * DD + tid] = s;
    }
}

// ---------------------------------------------------------------- fused per-(b,n) tree evaluation
__global__ __launch_bounds__(256)
void main_kernel(int J, const int* __restrict__ fj, const float* __restrict__ fv,
                 const int* __restrict__ fcnt, const float* __restrict__ es_sum,
                 const float* __restrict__ thr, const float* __restrict__ lt,
                 const float* __restrict__ resp,
                 float* __restrict__ out, int colOff) {
    int n = blockIdx.x;
    int b = blockIdx.y;
    int tid = threadIdx.x;
    __shared__ int   s_j[TDEPTH][MAXJ];
    __shared__ float s_v[TDEPTH][MAXJ];
    __shared__ int   s_cnt[TDEPTH];
    __shared__ float s_thr[TDEPTH], s_elt[TDEPTH];
    __shared__ float sb[TDEPTH][DD];
    __shared__ float red[8][DD];

    if (tid < TDEPTH) {
        int r = n * TDEPTH + tid;
        s_cnt[tid] = fcnt[r];
        s_thr[tid] = thr[r];
        s_elt[tid] = expf(-lt[r]);
    }
    __syncthreads();
    for (int idx = tid; idx < TDEPTH * J; idx += 256) {
        int t = idx / J, p = idx - t * J;
        if (p < s_cnt[t]) {
            size_t g = (size_t)(n * TDEPTH + t) * J + p;
            s_j[t][p] = fj[g];
            s_v[t][p] = fv[g];
        }
    }
    __syncthreads();

    // phase 1: sel -> sparsemoid, one thread per (t,d)
    if (tid < TDEPTH * DD) {
        int t = tid >> 5, d = tid & 31;
        const float* xb = out + (size_t)b * OUT_STRIDE;
        float acc = 0.f;
        int c = s_cnt[t];
        for (int p = 0; p < c; ++p) {
            acc += xb[s_j[t][p] * 32 + d] * s_v[t][p];
        }
        float sel = acc * es_sum[(size_t)(n * TDEPTH + t) * DD + d];
        float tlv = (sel - s_thr[t]) * s_elt[t];
        sb[t][d] = fminf(fmaxf(0.5f * tlv + 0.5f, 0.f), 1.f);
    }
    __syncthreads();

    // phase 2: 64-leaf product x resp; threads = (cc 0..7) x (d 0..31)
    {
        int cc = tid >> 5, d = tid & 31;
        float sv0 = sb[0][d], sv1 = sb[1][d], sv2 = sb[2][d];
        float sv3 = sb[3][d], sv4 = sb[4][d], sv5 = sb[5][d];
        const float4* rp = (const float4*)(resp + ((size_t)n * DD + d) * 64 + cc * 8);
        float4 r0 = rp[0], r1 = rp[1];
        float rr[8] = {r0.x, r0.y, r0.z, r0.w, r1.x, r1.y, r1.z, r1.w};
        float partial = 0.f;
        #pragma unroll
        for (int c2 = 0; c2 < 8; ++c2) {
            int c = cc * 8 + c2;
            float p = ((c >> 0) & 1) ? (1.f - sv0) : sv0;
            p *= ((c >> 1) & 1) ? (1.f - sv1) : sv1;
            p *= ((c >> 2) & 1) ? (1.f - sv2) : sv2;
            p *= ((c >> 3) & 1) ? (1.f - sv3) : sv3;
            p *= ((c >> 4) & 1) ? (1.f - sv4) : sv4;
            p *= ((c >> 5) & 1) ? (1.f - sv5) : sv5;
            partial += p * rr[c2];
        }
        red[cc][d] = partial;
    }
    __syncthreads();
    if (tid < DD) {
        float s = 0.f;
        #pragma unroll
        for (int g = 0; g < 8; ++g) s += red[g][tid];
        out[(size_t)b * OUT_STRIDE + (size_t)(colOff + n) * DD + tid] = s;
    }
}

// ----------------------------------------------------------------
extern "C" void kernel_launch(void* const* d_in, const int* in_sizes, int n_in,
                              void* d_out, int out_size, void* d_ws, size_t ws_size,
                              hipStream_t stream) {
    const float* x = (const float*)d_in[0];
    float* out = (float*)d_out;

    // workspace layout (reused across layers)
    char* ws = (char*)d_ws;
    int*   fj   = (int*)(ws);                                   // NT*MAXJ ints
    float* fv   = (float*)(ws + (size_t)NT * MAXJ * 4);         // NT*MAXJ floats
    int*   fcnt = (int*)(ws + (size_t)2 * NT * MAXJ * 4);       // NT ints
    float* ess  = (float*)(ws + (size_t)2 * NT * MAXJ * 4 + 1024 * 4); // NT*32 floats

    copy_x_kernel<<<(BB * 64 * DD + 255) / 256, 256, 0, stream>>>(x, out);

    const int Js[3] = {64, 192, 320};
    int colOff = 64;
    for (int L = 0; L < 3; ++L) {
        const float* fsl  = (const float*)d_in[1 + 5 * L];
        const float* esl  = (const float*)d_in[2 + 5 * L];
        const float* thr  = (const float*)d_in[3 + 5 * L];
        const float* lt   = (const float*)d_in[4 + 5 * L];
        const float* resp = (const float*)d_in[5 + 5 * L];
        int J = Js[L];

        fs_kernel<<<NT, 256, 0, stream>>>(fsl, J, fj, fv, fcnt);
        es_kernel<<<NT, 256, 0, stream>>>(esl, J, ess);
        main_kernel<<<dim3(NTREES, BB), 256, 0, stream>>>(
            J, fj, fv, fcnt, ess, thr, lt, resp, out, colOff);
        colOff += NTREES;
    }
}

// Round 2
// 261.585 us; speedup vs baseline: 1.0484x; 1.0484x over previous
//
#include <hip/hip_runtime.h>

#define OUT_COLS 448
#define OUT_STRIDE (OUT_COLS * 32)   // 14336 floats per batch row
#define NTREES 128
#define TDEPTH 6
#define NT (NTREES * TDEPTH)         // 768 rows
#define DD 32
#define BB 64
#define MAXJ 320

// ---------------------------------------------------------------- copy x into out[:, 0:64, :]
__global__ void copy_x_kernel(const float* __restrict__ x, float* __restrict__ out) {
    int idx = blockIdx.x * blockDim.x + threadIdx.x;
    if (idx < BB * 64 * DD) {
        int b = idx >> 11;        // / (64*32)
        int r = idx & 2047;
        out[(size_t)b * OUT_STRIDE + r] = x[idx];
    }
}

// ---------------------------------------------------------------- fused per-(n,t) prep:
//   phase A: sparsemax(fsl row) -> compacted (j,val) pairs via direct rank placement
//   phase B: es_sum[row][d] = sum_j sparsemax(esl[row,j,:])[d]
__global__ __launch_bounds__(256)
void prep_kernel(const float* __restrict__ fsl, const float* __restrict__ esl, int J,
                 int* __restrict__ fj, float* __restrict__ fv, int* __restrict__ fcnt,
                 float* __restrict__ es_sum) {
    int row = blockIdx.x;
    int tid = threadIdx.x;
    __shared__ float z[MAXJ];
    __shared__ int scount;
    __shared__ float ssum;
    __shared__ float red[8][DD];

    // ---- phase A: fs sparsemax ----
    const float* zr = fsl + (size_t)row * J;
    for (int i = tid; i < J; i += 256) z[i] = zr[i];
    if (tid == 0) scount = 0;
    __syncthreads();

    int i0 = tid, i1 = tid + 256;
    bool h0 = i0 < J, h1 = i1 < J;
    float z0 = h0 ? z[i0] : -1e30f;
    float z1 = h1 ? z[i1] : -1e30f;
    int c0 = 0, c1 = 0;
    float s0 = 0.f, s1 = 0.f;
    for (int jj = 0; jj < J; ++jj) {
        float zj = z[jj];
        if (zj > z0 || (zj == z0 && jj <= i0)) { c0++; s0 += zj; }
        if (zj > z1 || (zj == z1 && jj <= i1)) { c1++; s1 += zj; }
    }
    // support condition evaluated at this element's (unique) descending rank
    bool cd0 = h0 && ((float)c0 * z0 > s0 - 1.0f);
    bool cd1 = h1 && ((float)c1 * z1 > s1 - 1.0f);
    int loc = (cd0 ? 1 : 0) + (cd1 ? 1 : 0);
    if (loc) atomicAdd(&scount, loc);
    __syncthreads();
    int ks = scount;                        // k_sup (prefix property => count == max k)
    if (h0 && c0 == ks) ssum = s0;          // exactly one element has rank == ks
    if (h1 && c1 == ks) ssum = s1;
    __syncthreads();
    float tau = (ssum - 1.0f) / (float)ks;
    size_t base = (size_t)row * J;
    // support == ranks 1..ks; compacted position = rank-1 (no scan needed)
    if (h0 && c0 <= ks) { fj[base + c0 - 1] = i0; fv[base + c0 - 1] = fmaxf(z0 - tau, 0.f); }
    if (h1 && c1 <= ks) { fj[base + c1 - 1] = i1; fv[base + c1 - 1] = fmaxf(z1 - tau, 0.f); }
    if (tid == 0) fcnt[row] = ks;

    // ---- phase B: es sparsemax-sum ----
    int lg = tid & 31;       // lane within 32-group (= d)
    int grp = tid >> 5;      // 0..7
    float acc = 0.f;
    for (int j0 = 0; j0 < J; j0 += 8) {
        int j = j0 + grp;
        const float* er = esl + ((size_t)row * J + j) * 32;
        float zd = er[lg];
        float v = zd;
        // bitonic sort DESCENDING across the 32-lane group
        #pragma unroll
        for (int k = 2; k <= 32; k <<= 1) {
            #pragma unroll
            for (int jm = k >> 1; jm > 0; jm >>= 1) {
                float o = __shfl_xor(v, jm);
                bool lower = (lg & jm) == 0;
                bool asc = (lg & k) != 0;      // flipped -> overall descending
                v = (lower == asc) ? fminf(v, o) : fmaxf(v, o);
            }
        }
        // inclusive prefix sum within the 32-lane group
        float cum = v;
        #pragma unroll
        for (int off = 1; off < 32; off <<= 1) {
            float o = __shfl_up(cum, off, 32);
            if (lg >= off) cum += o;
        }
        bool sup = ((float)(lg + 1) * v > cum - 1.0f);
        unsigned long long m = __ballot(sup);
        unsigned mh = (tid & 32) ? (unsigned)(m >> 32) : (unsigned)(m & 0xffffffffu);
        int kse = __popc(mh);
        float tsum = __shfl(cum, kse - 1, 32);
        float taue = (tsum - 1.0f) / (float)kse;
        acc += fmaxf(zd - taue, 0.0f);
    }
    __syncthreads();
    red[grp][lg] = acc;
    __syncthreads();
    if (tid < 32) {
        float s = 0.f;
        #pragma unroll
        for (int g = 0; g < 8; ++g) s += red[g][tid];
        es_sum[(size_t)row * DD + tid] = s;
    }
}

// ---------------------------------------------------------------- fused per-(b,n) tree evaluation
__global__ __launch_bounds__(256)
void main_kernel(int J, const int* __restrict__ fj, const float* __restrict__ fv,
                 const int* __restrict__ fcnt, const float* __restrict__ es_sum,
                 const float* __restrict__ thr, const float* __restrict__ lt,
                 const float* __restrict__ resp,
                 float* __restrict__ out, int colOff) {
    int n = blockIdx.x;
    int b = blockIdx.y;
    int tid = threadIdx.x;
    __shared__ int   s_j[TDEPTH][MAXJ];
    __shared__ float s_v[TDEPTH][MAXJ];
    __shared__ int   s_cnt[TDEPTH];
    __shared__ float s_thr[TDEPTH], s_elt[TDEPTH];
    __shared__ float sb[TDEPTH][DD];
    __shared__ float red[8][DD];

    if (tid < TDEPTH) {
        int r = n * TDEPTH + tid;
        s_cnt[tid] = fcnt[r];
        s_thr[tid] = thr[r];
        s_elt[tid] = expf(-lt[r]);
    }
    __syncthreads();
    // load only the compacted entries (counts are ~sqrt(2J) ~ 12..26)
    #pragma unroll
    for (int t = 0; t < TDEPTH; ++t) {
        for (int p = tid; p < s_cnt[t]; p += 256) {
            size_t g = (size_t)(n * TDEPTH + t) * J + p;
            s_j[t][p] = fj[g];
            s_v[t][p] = fv[g];
        }
    }
    __syncthreads();

    // phase 1: sel -> sparsemoid, one thread per (t,d)
    if (tid < TDEPTH * DD) {
        int t = tid >> 5, d = tid & 31;
        const float* xb = out + (size_t)b * OUT_STRIDE;
        float acc = 0.f;
        int c = s_cnt[t];
        for (int p = 0; p < c; ++p) {
            acc += xb[s_j[t][p] * 32 + d] * s_v[t][p];
        }
        float sel = acc * es_sum[(size_t)(n * TDEPTH + t) * DD + d];
        float tlv = (sel - s_thr[t]) * s_elt[t];
        sb[t][d] = fminf(fmaxf(0.5f * tlv + 0.5f, 0.f), 1.f);
    }
    __syncthreads();

    // phase 2: 64-leaf product x resp; threads = (cc 0..7) x (d 0..31)
    {
        int cc = tid >> 5, d = tid & 31;
        float sv0 = sb[0][d], sv1 = sb[1][d], sv2 = sb[2][d];
        float sv3 = sb[3][d], sv4 = sb[4][d], sv5 = sb[5][d];
        const float4* rp = (const float4*)(resp + ((size_t)n * DD + d) * 64 + cc * 8);
        float4 r0 = rp[0], r1 = rp[1];
        float rr[8] = {r0.x, r0.y, r0.z, r0.w, r1.x, r1.y, r1.z, r1.w};
        float partial = 0.f;
        #pragma unroll
        for (int c2 = 0; c2 < 8; ++c2) {
            int c = cc * 8 + c2;
            float p = ((c >> 0) & 1) ? (1.f - sv0) : sv0;
            p *= ((c >> 1) & 1) ? (1.f - sv1) : sv1;
            p *= ((c >> 2) & 1) ? (1.f - sv2) : sv2;
            p *= ((c >> 3) & 1) ? (1.f - sv3) : sv3;
            p *= ((c >> 4) & 1) ? (1.f - sv4) : sv4;
            p *= ((c >> 5) & 1) ? (1.f - sv5) : sv5;
            partial += p * rr[c2];
        }
        red[cc][d] = partial;
    }
    __syncthreads();
    if (tid < DD) {
        float s = 0.f;
        #pragma unroll
        for (int g = 0; g < 8; ++g) s += red[g][tid];
        out[(size_t)b * OUT_STRIDE + (size_t)(colOff + n) * DD + tid] = s;
    }
}

// ----------------------------------------------------------------
extern "C" void kernel_launch(void* const* d_in, const int* in_sizes, int n_in,
                              void* d_out, int out_size, void* d_ws, size_t ws_size,
                              hipStream_t stream) {
    const float* x = (const float*)d_in[0];
    float* out = (float*)d_out;

    // workspace layout (reused across layers)
    char* ws = (char*)d_ws;
    int*   fj   = (int*)(ws);                                   // NT*MAXJ ints
    float* fv   = (float*)(ws + (size_t)NT * MAXJ * 4);         // NT*MAXJ floats
    int*   fcnt = (int*)(ws + (size_t)2 * NT * MAXJ * 4);       // NT ints
    float* ess  = (float*)(ws + (size_t)2 * NT * MAXJ * 4 + 1024 * 4); // NT*32 floats

    copy_x_kernel<<<(BB * 64 * DD + 255) / 256, 256, 0, stream>>>(x, out);

    const int Js[3] = {64, 192, 320};
    int colOff = 64;
    for (int L = 0; L < 3; ++L) {
        const float* fsl  = (const float*)d_in[1 + 5 * L];
        const float* esl  = (const float*)d_in[2 + 5 * L];
        const float* thr  = (const float*)d_in[3 + 5 * L];
        const float* lt   = (const float*)d_in[4 + 5 * L];
        const float* resp = (const float*)d_in[5 + 5 * L];
        int J = Js[L];

        prep_kernel<<<NT, 256, 0, stream>>>(fsl, esl, J, fj, fv, fcnt, ess);
        main_kernel<<<dim3(NTREES, BB), 256, 0, stream>>>(
            J, fj, fv, fcnt, ess, thr, lt, resp, out, colOff);
        colOff += NTREES;
    }
}

// Round 3
// 189.988 us; speedup vs baseline: 1.4435x; 1.3768x over previous
//
#include <hip/hip_runtime.h>

#define OUT_COLS 448
#define OUT_STRIDE (OUT_COLS * 32)   // 14336 floats per batch row
#define NTREES 128
#define TDEPTH 6
#define NT (NTREES * TDEPTH)         // 768 rows
#define DD 32
#define BB 64
#define MAXJ 320

// order-preserving float -> uint map (monotone: a<b  <=>  omap(a)<omap(b))
__device__ __forceinline__ unsigned omap(float f) {
    unsigned b = __float_as_uint(f);
    return (b & 0x80000000u) ? ~b : (b | 0x80000000u);
}

// ---------------------------------------------------------------- copy x into out[:, 0:64, :]
__global__ void copy_x_kernel(const float* __restrict__ x, float* __restrict__ out) {
    int idx = blockIdx.x * blockDim.x + threadIdx.x;
    if (idx < BB * 64 * DD) {
        int b = idx >> 11;
        int r = idx & 2047;
        out[(size_t)b * OUT_STRIDE + r] = x[idx];
    }
}

// ---------------------------------------------------------------- fs sparsemax, all 3 layers in one launch
// block = (row, layer); 512 threads, one target element per thread.
__global__ __launch_bounds__(512)
void fs_all_kernel(const float* __restrict__ f0, const float* __restrict__ f1,
                   const float* __restrict__ f2,
                   int* __restrict__ fj, float* __restrict__ fv, int* __restrict__ fcnt) {
    int row = blockIdx.x;
    int L = blockIdx.y;
    int tid = threadIdx.x;
    const float* fsl = (L == 0) ? f0 : (L == 1) ? f1 : f2;
    int J = (L == 0) ? 64 : (L == 1) ? 192 : 320;
    size_t lbase = (L == 0) ? 0 : (L == 1) ? (size_t)NT * 64 : (size_t)NT * 256;

    __shared__ unsigned long long skey[MAXJ];
    __shared__ float sz[MAXJ];
    __shared__ int scount;
    __shared__ float ssum;

    const float* zr = fsl + (size_t)row * J;
    for (int i = tid; i < J; i += 512) {
        float z = zr[i];
        sz[i] = z;
        skey[i] = ((unsigned long long)omap(z) << 32) | (unsigned)(0xffffffffu - (unsigned)i);
    }
    if (tid == 0) scount = 0;
    __syncthreads();

    bool act = tid < J;
    unsigned long long mk = act ? skey[tid] : ~0ull;
    float myz = act ? sz[tid] : 0.f;
    int c = 0; float s = 0.f;
    for (int jj = 0; jj < J; ++jj) {
        unsigned long long k = skey[jj];
        float zj = sz[jj];
        if (k >= mk) { c++; s += zj; }   // rank count + top-rank prefix sum (self included)
    }
    // support condition at this element's (unique) descending rank
    bool cd = act && ((float)c * myz > s - 1.0f);
    if (cd) atomicAdd(&scount, 1);
    __syncthreads();
    int ks = scount;                       // k_sup (support is a rank-prefix)
    if (act && c == ks) ssum = s;          // unique element with rank == ks
    __syncthreads();
    float tau = (ssum - 1.0f) / (float)ks;
    if (cd) {                               // cd <=> rank c <= ks; compacted pos = c-1
        size_t base = lbase + (size_t)row * J + (size_t)(c - 1);
        fj[base] = tid;
        fv[base] = fmaxf(myz - tau, 0.f);
    }
    if (tid == 0) fcnt[L * NT + row] = ks;
}

// ---------------------------------------------------------------- es partial sums, all layers
// block = (row, chunk-of-64-j, layer); 8 lane-groups of 32 do 8 j-rows/pass, 8 passes.
__global__ __launch_bounds__(256)
void es_all_kernel(const float* __restrict__ e0, const float* __restrict__ e1,
                   const float* __restrict__ e2, float* __restrict__ part) {
    int row = blockIdx.x, chunk = blockIdx.y, L = blockIdx.z;
    int J = (L == 0) ? 64 : (L == 1) ? 192 : 320;
    int nch = J >> 6;
    if (chunk >= nch) return;
    const float* esl = (L == 0) ? e0 : (L == 1) ? e1 : e2;
    int tid = threadIdx.x, lg = tid & 31, grp = tid >> 5;

    const float* rowp = esl + (size_t)row * J * 32;
    float acc = 0.f;
    #pragma unroll
    for (int j0 = 0; j0 < 64; j0 += 8) {
        int j = chunk * 64 + j0 + grp;
        float zd = rowp[(size_t)j * 32 + lg];
        float v = zd;
        // bitonic sort DESCENDING across the 32-lane group
        #pragma unroll
        for (int k = 2; k <= 32; k <<= 1) {
            #pragma unroll
            for (int jm = k >> 1; jm > 0; jm >>= 1) {
                float o = __shfl_xor(v, jm);
                bool lower = (lg & jm) == 0;
                bool asc = (lg & k) != 0;
                v = (lower == asc) ? fminf(v, o) : fmaxf(v, o);
            }
        }
        // inclusive prefix sum within the 32-lane group
        float cum = v;
        #pragma unroll
        for (int off = 1; off < 32; off <<= 1) {
            float o = __shfl_up(cum, off, 32);
            if (lg >= off) cum += o;
        }
        bool sup = ((float)(lg + 1) * v > cum - 1.0f);
        unsigned long long m = __ballot(sup);
        unsigned mh = (tid & 32) ? (unsigned)(m >> 32) : (unsigned)(m & 0xffffffffu);
        int kse = __popc(mh);
        float tsum = __shfl(cum, kse - 1, 32);
        float taue = (tsum - 1.0f) / (float)kse;
        acc += fmaxf(zd - taue, 0.0f);
    }
    __shared__ float red[8][DD];
    red[grp][lg] = acc;
    __syncthreads();
    if (tid < 32) {
        float s = 0.f;
        #pragma unroll
        for (int g = 0; g < 8; ++g) s += red[g][tid];
        part[(((size_t)L * NT + row) * 5 + chunk) * 32 + tid] = s;
    }
}

// ---------------------------------------------------------------- deterministic chunk reduction
__global__ void es_reduce_kernel(const float* __restrict__ part, float* __restrict__ ess) {
    int idx = blockIdx.x * blockDim.x + threadIdx.x;
    if (idx >= 3 * NT * 32) return;
    int L = idx / (NT * 32);
    int rd = idx - L * (NT * 32);
    int nch = (L == 0) ? 1 : (L == 1) ? 3 : 5;
    int row = rd >> 5, d = rd & 31;
    float s = 0.f;
    for (int c = 0; c < nch; ++c)
        s += part[(((size_t)L * NT + row) * 5 + c) * 32 + d];
    ess[idx] = s;   // layout [L][row][32]
}

// ---------------------------------------------------------------- fused per-(b,n) tree evaluation
__global__ __launch_bounds__(256)
void main_kernel(int J, const int* __restrict__ fj, const float* __restrict__ fv,
                 const int* __restrict__ fcnt, const float* __restrict__ es_sum,
                 const float* __restrict__ thr, const float* __restrict__ lt,
                 const float* __restrict__ resp,
                 float* __restrict__ out, int colOff) {
    int n = blockIdx.x;
    int b = blockIdx.y;
    int tid = threadIdx.x;
    __shared__ int   s_j[TDEPTH][MAXJ];
    __shared__ float s_v[TDEPTH][MAXJ];
    __shared__ int   s_cnt[TDEPTH];
    __shared__ float s_thr[TDEPTH], s_elt[TDEPTH];
    __shared__ float sb[TDEPTH][DD];
    __shared__ float red[8][DD];

    if (tid < TDEPTH) {
        int r = n * TDEPTH + tid;
        s_cnt[tid] = fcnt[r];
        s_thr[tid] = thr[r];
        s_elt[tid] = expf(-lt[r]);
    }
    __syncthreads();
    #pragma unroll
    for (int t = 0; t < TDEPTH; ++t) {
        for (int p = tid; p < s_cnt[t]; p += 256) {
            size_t g = (size_t)(n * TDEPTH + t) * J + p;
            s_j[t][p] = fj[g];
            s_v[t][p] = fv[g];
        }
    }
    __syncthreads();

    // phase 1: sel -> sparsemoid, one thread per (t,d)
    if (tid < TDEPTH * DD) {
        int t = tid >> 5, d = tid & 31;
        const float* xb = out + (size_t)b * OUT_STRIDE;
        float acc = 0.f;
        int c = s_cnt[t];
        for (int p = 0; p < c; ++p) {
            acc += xb[s_j[t][p] * 32 + d] * s_v[t][p];
        }
        float sel = acc * es_sum[(size_t)(n * TDEPTH + t) * DD + d];
        float tlv = (sel - s_thr[t]) * s_elt[t];
        sb[t][d] = fminf(fmaxf(0.5f * tlv + 0.5f, 0.f), 1.f);
    }
    __syncthreads();

    // phase 2: 64-leaf product x resp; threads = (cc 0..7) x (d 0..31)
    {
        int cc = tid >> 5, d = tid & 31;
        float sv0 = sb[0][d], sv1 = sb[1][d], sv2 = sb[2][d];
        float sv3 = sb[3][d], sv4 = sb[4][d], sv5 = sb[5][d];
        const float4* rp = (const float4*)(resp + ((size_t)n * DD + d) * 64 + cc * 8);
        float4 r0 = rp[0], r1 = rp[1];
        float rr[8] = {r0.x, r0.y, r0.z, r0.w, r1.x, r1.y, r1.z, r1.w};
        float partial = 0.f;
        #pragma unroll
        for (int c2 = 0; c2 < 8; ++c2) {
            int c = cc * 8 + c2;
            float p = ((c >> 0) & 1) ? (1.f - sv0) : sv0;
            p *= ((c >> 1) & 1) ? (1.f - sv1) : sv1;
            p *= ((c >> 2) & 1) ? (1.f - sv2) : sv2;
            p *= ((c >> 3) & 1) ? (1.f - sv3) : sv3;
            p *= ((c >> 4) & 1) ? (1.f - sv4) : sv4;
            p *= ((c >> 5) & 1) ? (1.f - sv5) : sv5;
            partial += p * rr[c2];
        }
        red[cc][d] = partial;
    }
    __syncthreads();
    if (tid < DD) {
        float s = 0.f;
        #pragma unroll
        for (int g = 0; g < 8; ++g) s += red[g][tid];
        out[(size_t)b * OUT_STRIDE + (size_t)(colOff + n) * DD + tid] = s;
    }
}

// ----------------------------------------------------------------
extern "C" void kernel_launch(void* const* d_in, const int* in_sizes, int n_in,
                              void* d_out, int out_size, void* d_ws, size_t ws_size,
                              hipStream_t stream) {
    const float* x = (const float*)d_in[0];
    float* out = (float*)d_out;

    // workspace layout
    const size_t NFS = (size_t)NT * (64 + 192 + 320);   // 442368 compacted slots
    char* ws = (char*)d_ws;
    int*   fj   = (int*)(ws);
    float* fv   = (float*)(ws + NFS * 4);
    int*   fcnt = (int*)(ws + 2 * NFS * 4);
    float* ess  = (float*)(ws + 2 * NFS * 4 + 16384);             // [3][NT][32]
    float* part = (float*)(ws + 2 * NFS * 4 + 16384 + 3 * NT * 32 * 4); // [3][NT][5][32]

    copy_x_kernel<<<(BB * 64 * DD + 255) / 256, 256, 0, stream>>>(x, out);

    fs_all_kernel<<<dim3(NT, 3), 512, 0, stream>>>(
        (const float*)d_in[1], (const float*)d_in[6], (const float*)d_in[11],
        fj, fv, fcnt);
    es_all_kernel<<<dim3(NT, 5, 3), 256, 0, stream>>>(
        (const float*)d_in[2], (const float*)d_in[7], (const float*)d_in[12], part);
    es_reduce_kernel<<<(3 * NT * 32 + 255) / 256, 256, 0, stream>>>(part, ess);

    const int Js[3] = {64, 192, 320};
    const size_t lbase[3] = {0, (size_t)NT * 64, (size_t)NT * 256};
    int colOff = 64;
    for (int L = 0; L < 3; ++L) {
        const float* thr  = (const float*)d_in[3 + 5 * L];
        const float* lt   = (const float*)d_in[4 + 5 * L];
        const float* resp = (const float*)d_in[5 + 5 * L];
        main_kernel<<<dim3(NTREES, BB), 256, 0, stream>>>(
            Js[L], fj + lbase[L], fv + lbase[L], fcnt + L * NT, ess + (size_t)L * NT * 32,
            thr, lt, resp, out, colOff);
        colOff += NTREES;
    }
}

// Round 4
// 157.187 us; speedup vs baseline: 1.7448x; 1.2087x over previous
//
#include <hip/hip_runtime.h>

#define OUT_COLS 448
#define OUT_STRIDE (OUT_COLS * 32)   // 14336 floats per batch row
#define NTREES 128
#define TDEPTH 6
#define NT (NTREES * TDEPTH)         // 768 rows
#define DD 32
#define BB 64
#define PADW 64                      // padded compacted width for fs output

// order-preserving float -> uint map (monotone: a<b  <=>  omap(a)<omap(b))
__device__ __forceinline__ unsigned omap(float f) {
    unsigned b = __float_as_uint(f);
    return (b & 0x80000000u) ? ~b : (b | 0x80000000u);
}

// DPP mov helper (compile-time ctrl)
template <int CTRL, int RMASK = 0xf, bool BC = true>
__device__ __forceinline__ float dppf(float v) {
    return __int_as_float(
        __builtin_amdgcn_update_dpp(0, __float_as_int(v), CTRL, RMASK, 0xf, BC));
}

// bitonic compare-exchange step across lanes (descending overall), partner = lane^JM
template <int K, int JM>
__device__ __forceinline__ float cex(float v, int lg) {
    float o;
    if constexpr (JM == 1)      o = dppf<0xB1>(v);               // quad_perm [1,0,3,2]
    else if constexpr (JM == 2) o = dppf<0x4E>(v);               // quad_perm [2,3,0,1]
    else o = __int_as_float(__builtin_amdgcn_ds_swizzle(__float_as_int(v), (JM << 10) | 0x1F));
    bool lower = (lg & JM) == 0;
    bool asc   = (lg & K) != 0;
    return (lower == asc) ? fminf(v, o) : fmaxf(v, o);
}

__device__ __forceinline__ float sort32_desc(float v, int lg) {
    v = cex<2, 1>(v, lg);
    v = cex<4, 2>(v, lg);  v = cex<4, 1>(v, lg);
    v = cex<8, 4>(v, lg);  v = cex<8, 2>(v, lg);  v = cex<8, 1>(v, lg);
    v = cex<16, 8>(v, lg); v = cex<16, 4>(v, lg); v = cex<16, 2>(v, lg); v = cex<16, 1>(v, lg);
    v = cex<32, 16>(v, lg); v = cex<32, 8>(v, lg); v = cex<32, 4>(v, lg);
    v = cex<32, 2>(v, lg);  v = cex<32, 1>(v, lg);
    return v;
}

// inclusive prefix sum within each 32-lane group (DPP, 0 DS ops)
__device__ __forceinline__ float scan32_incl(float x) {
    x += dppf<0x111>(x);   // row_shr:1
    x += dppf<0x112>(x);   // row_shr:2
    x += dppf<0x114>(x);   // row_shr:4
    x += dppf<0x118>(x);   // row_shr:8  -> per-16-row inclusive scan
    // lanes 16-31 += lane15 total; lanes 48-63 += lane47 (row_bcast15, rows 1&3)
    x += __int_as_float(__builtin_amdgcn_update_dpp(0, __float_as_int(x), 0x142, 0xa, 0xf, false));
    return x;
}

// full sparsemax contribution for one 32-element row held across a 32-lane group
__device__ __forceinline__ float es_one(float zd, int lg, int tid) {
    float v = sort32_desc(zd, lg);
    float cum = scan32_incl(v);
    bool sup = ((float)(lg + 1) * v > cum - 1.0f);
    unsigned long long m = __ballot(sup);
    unsigned mh = (tid & 32) ? (unsigned)(m >> 32) : (unsigned)m;
    int ks = __popc(mh);
    float tsum = __shfl(cum, ks - 1, 32);
    float tau = (tsum - 1.0f) / (float)ks;
    return fmaxf(zd - tau, 0.0f);
}

// ---------------------------------------------------------------- copy x into out[:, 0:64, :]
__global__ void copy_x_kernel(const float* __restrict__ x, float* __restrict__ out) {
    int idx = blockIdx.x * blockDim.x + threadIdx.x;
    if (idx < BB * 64 * DD) {
        int b = idx >> 11;
        int r = idx & 2047;
        out[(size_t)b * OUT_STRIDE + r] = x[idx];
    }
}

// ---------------------------------------------------------------- fs sparsemax (row in registers,
// all-pairs rank via v_readlane broadcast — zero DS in the hot loop). Output zero-padded to PADW.
template <int J>
__global__ __launch_bounds__(512)
void fs_all_kernel(const float* __restrict__ fsl, int* __restrict__ fjp,
                   float* __restrict__ fvp, int* __restrict__ fcnt) {
    constexpr int TILES = J / 64;
    int row = blockIdx.x;
    int tid = threadIdx.x;
    int lane = tid & 63;
    __shared__ int scount;
    __shared__ float ssum;
    size_t rowbase = (size_t)row * PADW;
    if (tid < PADW) { fjp[rowbase + tid] = 0; fvp[rowbase + tid] = 0.f; }
    if (tid == 0) scount = 0;

    const float* zr = fsl + (size_t)row * J;
    float zz[TILES]; int kk[TILES];
    #pragma unroll
    for (int t = 0; t < TILES; ++t) {
        zz[t] = zr[t * 64 + lane];
        kk[t] = (int)omap(zz[t]);
    }
    bool act = tid < J;
    float myz = 0.f;
    if (act) myz = zr[tid];
    unsigned long long mk = act ? (((unsigned long long)omap(myz) << 32)
                                   | (unsigned)(0xffffffffu - (unsigned)tid))
                               : ~0ull;
    int c = 0; float s = 0.f;
    #pragma unroll
    for (int t = 0; t < TILES; ++t) {
        #pragma unroll
        for (int l = 0; l < 64; ++l) {
            unsigned sk = (unsigned)__builtin_amdgcn_readlane(kk[t], l);
            float sz = __int_as_float(__builtin_amdgcn_readlane(__float_as_int(zz[t]), l));
            unsigned long long bk = ((unsigned long long)sk << 32)
                                  | (unsigned)(0xffffffffu - (unsigned)(t * 64 + l));
            bool ge = bk >= mk;           // descending rank count, self included
            c += ge ? 1 : 0;
            s += ge ? sz : 0.f;
        }
    }
    __syncthreads();   // orders zero-fill/scount-init before the writes below
    bool cd = act && ((float)c * myz > s - 1.0f);
    if (cd) atomicAdd(&scount, 1);
    __syncthreads();
    int ks = scount;                      // k_sup (support is a rank prefix)
    if (act && c == ks) ssum = s;         // unique rank-ks element
    __syncthreads();
    float tau = (ssum - 1.0f) / (float)ks;
    if (cd && c <= PADW) {
        fjp[rowbase + (c - 1)] = tid;     // compacted position = rank-1
        fvp[rowbase + (c - 1)] = fmaxf(myz - tau, 0.f);
    }
    if (tid == 0) fcnt[row] = (ks < PADW) ? ks : PADW;
}

// ---------------------------------------------------------------- es partial sums (DPP sort/scan)
template <int J>
__global__ __launch_bounds__(256)
void es_all_kernel(const float* __restrict__ esl, float* __restrict__ part) {
    int row = blockIdx.x, chunk = blockIdx.y;
    int tid = threadIdx.x, lg = tid & 31, grp = tid >> 5;
    const float* rowp = esl + ((size_t)row * J + chunk * 64) * 32;
    float acc = 0.f;
    #pragma unroll
    for (int j0 = 0; j0 < 64; j0 += 16) {   // 2 independent rows per pass for ILP
        float zA = rowp[(size_t)(j0 + grp) * 32 + lg];
        float zB = rowp[(size_t)(j0 + 8 + grp) * 32 + lg];
        acc += es_one(zA, lg, tid);
        acc += es_one(zB, lg, tid);
    }
    __shared__ float red[8][DD];
    red[grp][lg] = acc;
    __syncthreads();
    if (tid < 32) {
        float s2 = 0.f;
        #pragma unroll
        for (int g = 0; g < 8; ++g) s2 += red[g][tid];
        part[((size_t)row * 5 + chunk) * 32 + tid] = s2;
    }
}

// ---------------------------------------------------------------- deterministic chunk reduction
__global__ void es_reduce_kernel(const float* __restrict__ part, float* __restrict__ ess) {
    int idx = blockIdx.x * blockDim.x + threadIdx.x;
    if (idx >= 3 * NT * 32) return;
    int L = idx / (NT * 32);
    int rd = idx - L * (NT * 32);
    int nch = (L == 0) ? 1 : (L == 1) ? 3 : 5;
    int row = rd >> 5, d = rd & 31;
    float s = 0.f;
    for (int c = 0; c < nch; ++c)
        s += part[(((size_t)L * NT + row) * 5 + c) * 32 + d];
    ess[idx] = s;   // layout [L][row][32]
}

// ---------------------------------------------------------------- fused per-(b,n) tree evaluation
__global__ __launch_bounds__(256)
void main_kernel(const int* __restrict__ fjp, const float* __restrict__ fvp,
                 const int* __restrict__ fcnt, const float* __restrict__ ess,
                 const float* __restrict__ thr, const float* __restrict__ lt,
                 const float* __restrict__ resp,
                 float* __restrict__ out, int colOff) {
    int n = blockIdx.x;
    int b = blockIdx.y;
    int tid = threadIdx.x;
    __shared__ int   s_j[TDEPTH][PADW];
    __shared__ float s_v[TDEPTH][PADW];
    __shared__ int   s_cnt[TDEPTH];
    __shared__ float s_thr[TDEPTH], s_elt[TDEPTH];
    __shared__ float sb[TDEPTH][DD];
    __shared__ float red[8][DD];

    if (tid < TDEPTH) {
        int r = n * TDEPTH + tid;
        s_cnt[tid] = fcnt[r];
        s_thr[tid] = thr[r];
        s_elt[tid] = expf(-lt[r]);
    }
    for (int i = tid; i < TDEPTH * PADW; i += 256) {
        int t = i >> 6, p = i & 63;
        size_t g = (size_t)(n * TDEPTH + t) * PADW + p;
        s_j[t][p] = fjp[g];
        s_v[t][p] = fvp[g];
    }
    __syncthreads();

    // phase 1: sel -> sparsemoid, one thread per (t,d); zero-padded 8-unrolled gather
    if (tid < TDEPTH * DD) {
        int t = tid >> 5, d = tid & 31;
        const float* xb = out + (size_t)b * OUT_STRIDE;
        float acc = 0.f;
        int c8 = (s_cnt[t] + 7) & ~7;
        for (int p = 0; p < c8; p += 8) {
            #pragma unroll
            for (int q = 0; q < 8; ++q)
                acc += xb[s_j[t][p + q] * 32 + d] * s_v[t][p + q];
        }
        float sel = acc * ess[(size_t)(n * TDEPTH + t) * DD + d];
        float tlv = (sel - s_thr[t]) * s_elt[t];
        sb[t][d] = fminf(fmaxf(0.5f * tlv + 0.5f, 0.f), 1.f);
    }
    __syncthreads();

    // phase 2: 64-leaf product x resp; threads = (cc 0..7) x (d 0..31)
    {
        int cc = tid >> 5, d = tid & 31;
        float sv0 = sb[0][d], sv1 = sb[1][d], sv2 = sb[2][d];
        float sv3 = sb[3][d], sv4 = sb[4][d], sv5 = sb[5][d];
        const float4* rp = (const float4*)(resp + ((size_t)n * DD + d) * 64 + cc * 8);
        float4 r0 = rp[0], r1 = rp[1];
        float rr[8] = {r0.x, r0.y, r0.z, r0.w, r1.x, r1.y, r1.z, r1.w};
        float partial = 0.f;
        #pragma unroll
        for (int c2 = 0; c2 < 8; ++c2) {
            int c = cc * 8 + c2;
            float p = ((c >> 0) & 1) ? (1.f - sv0) : sv0;
            p *= ((c >> 1) & 1) ? (1.f - sv1) : sv1;
            p *= ((c >> 2) & 1) ? (1.f - sv2) : sv2;
            p *= ((c >> 3) & 1) ? (1.f - sv3) : sv3;
            p *= ((c >> 4) & 1) ? (1.f - sv4) : sv4;
            p *= ((c >> 5) & 1) ? (1.f - sv5) : sv5;
            partial += p * rr[c2];
        }
        red[cc][d] = partial;
    }
    __syncthreads();
    if (tid < DD) {
        float s = 0.f;
        #pragma unroll
        for (int g = 0; g < 8; ++g) s += red[g][tid];
        out[(size_t)b * OUT_STRIDE + (size_t)(colOff + n) * DD + tid] = s;
    }
}

// ----------------------------------------------------------------
extern "C" void kernel_launch(void* const* d_in, const int* in_sizes, int n_in,
                              void* d_out, int out_size, void* d_ws, size_t ws_size,
                              hipStream_t stream) {
    const float* x = (const float*)d_in[0];
    float* out = (float*)d_out;

    // workspace layout
    const size_t NPAD = (size_t)3 * NT * PADW;   // 147456
    char* ws = (char*)d_ws;
    int*   fjp  = (int*)(ws);
    float* fvp  = (float*)(ws + NPAD * 4);
    int*   fcnt = (int*)(ws + 2 * NPAD * 4);
    float* ess  = (float*)(ws + 2 * NPAD * 4 + 16384);                  // [3][NT][32]
    float* part = (float*)(ws + 2 * NPAD * 4 + 16384 + (size_t)3 * NT * 32 * 4); // [3][NT][5][32]

    copy_x_kernel<<<(BB * 64 * DD + 255) / 256, 256, 0, stream>>>(x, out);

    fs_all_kernel<64 ><<<NT, 512, 0, stream>>>((const float*)d_in[1],
        fjp, fvp, fcnt);
    fs_all_kernel<192><<<NT, 512, 0, stream>>>((const float*)d_in[6],
        fjp + (size_t)NT * PADW, fvp + (size_t)NT * PADW, fcnt + NT);
    fs_all_kernel<320><<<NT, 512, 0, stream>>>((const float*)d_in[11],
        fjp + (size_t)2 * NT * PADW, fvp + (size_t)2 * NT * PADW, fcnt + 2 * NT);

    es_all_kernel<64 ><<<dim3(NT, 1), 256, 0, stream>>>((const float*)d_in[2],  part);
    es_all_kernel<192><<<dim3(NT, 3), 256, 0, stream>>>((const float*)d_in[7],  part + (size_t)NT * 5 * 32);
    es_all_kernel<320><<<dim3(NT, 5), 256, 0, stream>>>((const float*)d_in[12], part + (size_t)2 * NT * 5 * 32);
    es_reduce_kernel<<<(3 * NT * 32 + 255) / 256, 256, 0, stream>>>(part, ess);

    int colOff = 64;
    for (int L = 0; L < 3; ++L) {
        const float* thr  = (const float*)d_in[3 + 5 * L];
        const float* lt   = (const float*)d_in[4 + 5 * L];
        const float* resp = (const float*)d_in[5 + 5 * L];
        main_kernel<<<dim3(NTREES, BB), 256, 0, stream>>>(
            fjp + (size_t)L * NT * PADW, fvp + (size_t)L * NT * PADW,
            fcnt + L * NT, ess + (size_t)L * NT * 32,
            thr, lt, resp, out, colOff);
        colOff += NTREES;
    }
}

// Round 5
// 110.286 us; speedup vs baseline: 2.4868x; 1.4253x over previous
//
#include <hip/hip_runtime.h>

#define OUT_COLS 448
#define OUT_STRIDE (OUT_COLS * 32)   // 14336 floats per batch row
#define NTREES 128
#define TDEPTH 6
#define NT (NTREES * TDEPTH)         // 768 rows per layer
#define DD 32
#define BB 64
#define PADW 64                      // padded compacted width for fs output

// DPP mov helper (compile-time ctrl)
template <int CTRL, int RMASK = 0xf, bool BC = true>
__device__ __forceinline__ float dppf(float v) {
    return __int_as_float(
        __builtin_amdgcn_update_dpp(0, __float_as_int(v), CTRL, RMASK, 0xf, BC));
}

// full-wave (64-lane) sum, result broadcast to all lanes via readlane
__device__ __forceinline__ float wred64(float x) {
    x += dppf<0x111>(x);   // row_shr:1
    x += dppf<0x112>(x);   // row_shr:2
    x += dppf<0x114>(x);   // row_shr:4
    x += dppf<0x118>(x);   // row_shr:8   -> per-16 inclusive
    x += __int_as_float(__builtin_amdgcn_update_dpp(0, __float_as_int(x), 0x142, 0xa, 0xf, false)); // row_bcast15
    x += __int_as_float(__builtin_amdgcn_update_dpp(0, __float_as_int(x), 0x143, 0xc, 0xf, false)); // row_bcast31
    return __int_as_float(__builtin_amdgcn_readlane(__float_as_int(x), 63));
}

// bitonic compare-exchange across lanes (descending overall), partner = lane^JM
template <int K, int JM>
__device__ __forceinline__ float cex(float v, int lg) {
    float o;
    if constexpr (JM == 1)      o = dppf<0xB1>(v);               // quad_perm [1,0,3,2]
    else if constexpr (JM == 2) o = dppf<0x4E>(v);               // quad_perm [2,3,0,1]
    else o = __int_as_float(__builtin_amdgcn_ds_swizzle(__float_as_int(v), (JM << 10) | 0x1F));
    bool lower = (lg & JM) == 0;
    bool asc   = (lg & K) != 0;
    return (lower == asc) ? fminf(v, o) : fmaxf(v, o);
}

__device__ __forceinline__ float sort32_desc(float v, int lg) {
    v = cex<2, 1>(v, lg);
    v = cex<4, 2>(v, lg);  v = cex<4, 1>(v, lg);
    v = cex<8, 4>(v, lg);  v = cex<8, 2>(v, lg);  v = cex<8, 1>(v, lg);
    v = cex<16, 8>(v, lg); v = cex<16, 4>(v, lg); v = cex<16, 2>(v, lg); v = cex<16, 1>(v, lg);
    v = cex<32, 16>(v, lg); v = cex<32, 8>(v, lg); v = cex<32, 4>(v, lg);
    v = cex<32, 2>(v, lg);  v = cex<32, 1>(v, lg);
    return v;
}

// inclusive prefix sum within each 32-lane group (DPP, 0 DS ops)
__device__ __forceinline__ float scan32_incl(float x) {
    x += dppf<0x111>(x);
    x += dppf<0x112>(x);
    x += dppf<0x114>(x);
    x += dppf<0x118>(x);
    x += __int_as_float(__builtin_amdgcn_update_dpp(0, __float_as_int(x), 0x142, 0xa, 0xf, false));
    return x;
}

// sparsemax contribution for one 32-element row held across a 32-lane group
__device__ __forceinline__ float es_one(float zd, int lg, int tid) {
    float v = sort32_desc(zd, lg);
    float cum = scan32_incl(v);
    bool sup = ((float)(lg + 1) * v > cum - 1.0f);
    unsigned long long m = __ballot(sup);
    unsigned mh = (tid & 32) ? (unsigned)(m >> 32) : (unsigned)m;
    int ks = __popc(mh);
    float tsum = __shfl(cum, ks - 1, 32);
    float tau = (tsum - 1.0f) / (float)ks;
    return fmaxf(zd - tau, 0.0f);
}

// ---------------------------------------------------------------- copy x into out[:, 0:64, :]
__global__ void copy_x_kernel(const float* __restrict__ x, float* __restrict__ out) {
    int idx = blockIdx.x * blockDim.x + threadIdx.x;
    if (idx < BB * 64 * DD) {
        int b = idx >> 11;
        int r = idx & 2047;
        out[(size_t)b * OUT_STRIDE + r] = x[idx];
    }
}

// ---------------------------------------------------------------- fs sparsemax via Michelot
// One wave per row. Fixpoint: tau=(S-1)/k over shrinking active set {z>tau}.
template <int J>
__device__ __forceinline__ void fs_row(const float* __restrict__ zr, int lane,
                                       int* __restrict__ fj, float* __restrict__ fv,
                                       int* __restrict__ fcnt_p) {
    constexpr int T = J / 64;
    float z[T];
    #pragma unroll
    for (int t = 0; t < T; ++t) z[t] = zr[t * 64 + lane];
    float sp = 0.f;
    #pragma unroll
    for (int t = 0; t < T; ++t) sp += z[t];
    float k = (float)J;
    float tau = (wred64(sp) - 1.f) / k;
    #pragma unroll 1
    for (int it = 0; it < 64; ++it) {
        float s2 = 0.f, c2 = 0.f;
        #pragma unroll
        for (int t = 0; t < T; ++t) {
            bool g = z[t] > tau;
            s2 += g ? z[t] : 0.f;
            c2 += g ? 1.f : 0.f;
        }
        float S2 = wred64(s2);
        float K2 = wred64(c2);
        if (K2 == k) break;            // active set stopped shrinking -> fixpoint
        k = K2;
        tau = (S2 - 1.f) / K2;
    }
    // ballot/popcount compaction (order-free: main only does dot products)
    unsigned long long below = (1ull << lane) - 1ull;
    int base = 0;
    #pragma unroll
    for (int t = 0; t < T; ++t) {
        bool sup = z[t] > tau;
        unsigned long long m = __ballot(sup);
        int pos = base + __popcll(m & below);
        if (sup && pos < PADW) { fj[pos] = t * 64 + lane; fv[pos] = z[t] - tau; }
        base += __popcll(m);
    }
    int cnt = base < PADW ? base : PADW;
    for (int i = cnt + lane; i < PADW; i += 64) { fj[i] = 0; fv[i] = 0.f; }
    if (lane == 0) *fcnt_p = cnt;
}

__global__ __launch_bounds__(256)
void fs_kernel(const float* __restrict__ f0, const float* __restrict__ f1,
               const float* __restrict__ f2,
               int* __restrict__ fjp, float* __restrict__ fvp, int* __restrict__ fcnt) {
    int w = blockIdx.x * 4 + (threadIdx.x >> 6);   // 0..2303
    int lane = threadIdx.x & 63;
    if (w < NT) {
        fs_row<64>(f0 + (size_t)w * 64, lane,
                   fjp + (size_t)w * PADW, fvp + (size_t)w * PADW, fcnt + w);
    } else if (w < 2 * NT) {
        int r = w - NT;
        fs_row<192>(f1 + (size_t)r * 192, lane,
                    fjp + ((size_t)(NT + r)) * PADW, fvp + ((size_t)(NT + r)) * PADW,
                    fcnt + NT + r);
    } else {
        int r = w - 2 * NT;
        fs_row<320>(f2 + (size_t)r * 320, lane,
                    fjp + ((size_t)(2 * NT + r)) * PADW, fvp + ((size_t)(2 * NT + r)) * PADW,
                    fcnt + 2 * NT + r);
    }
}

// ---------------------------------------------------------------- es partial sums, single launch
// grid = (NT, 9): y decodes (layer, chunk-of-64-j). part layout [3*NT][5][32].
__global__ __launch_bounds__(256)
void es_kernel(const float* __restrict__ e0, const float* __restrict__ e1,
               const float* __restrict__ e2, float* __restrict__ part) {
    int row = blockIdx.x;
    int y = blockIdx.y;
    int L = (y == 0) ? 0 : (y <= 3) ? 1 : 2;
    int chunk = (y == 0) ? 0 : (y <= 3) ? y - 1 : y - 4;
    int J = (L == 0) ? 64 : (L == 1) ? 192 : 320;
    const float* esl = (L == 0) ? e0 : (L == 1) ? e1 : e2;
    int tid = threadIdx.x, lg = tid & 31, grp = tid >> 5;

    const float* rowp = esl + ((size_t)row * J + chunk * 64) * 32;
    float acc = 0.f;
    #pragma unroll
    for (int j0 = 0; j0 < 64; j0 += 16) {   // 2 independent rows per pass for ILP
        float zA = rowp[(size_t)(j0 + grp) * 32 + lg];
        float zB = rowp[(size_t)(j0 + 8 + grp) * 32 + lg];
        acc += es_one(zA, lg, tid);
        acc += es_one(zB, lg, tid);
    }
    __shared__ float red[8][DD];
    red[grp][lg] = acc;
    __syncthreads();
    if (tid < 32) {
        float s2 = 0.f;
        #pragma unroll
        for (int g = 0; g < 8; ++g) s2 += red[g][tid];
        part[(((size_t)L * NT + row) * 5 + chunk) * 32 + tid] = s2;
    }
}

// ---------------------------------------------------------------- fused per-(b,n) tree evaluation
__global__ __launch_bounds__(256)
void main_kernel(const int* __restrict__ fjp, const float* __restrict__ fvp,
                 const int* __restrict__ fcnt, const float* __restrict__ partL, int nch,
                 const float* __restrict__ thr, const float* __restrict__ lt,
                 const float* __restrict__ resp,
                 float* __restrict__ out, int colOff) {
    int n = blockIdx.x;
    int b = blockIdx.y;
    int tid = threadIdx.x;
    __shared__ int   s_j[TDEPTH][PADW];
    __shared__ float s_v[TDEPTH][PADW];
    __shared__ int   s_cnt[TDEPTH];
    __shared__ float s_thr[TDEPTH], s_elt[TDEPTH];
    __shared__ float sb[TDEPTH][DD];
    __shared__ float red[8][DD];

    if (tid < TDEPTH) {
        int r = n * TDEPTH + tid;
        s_cnt[tid] = fcnt[r];
        s_thr[tid] = thr[r];
        s_elt[tid] = expf(-lt[r]);
    }
    for (int i = tid; i < TDEPTH * PADW; i += 256) {
        int t = i >> 6, p = i & 63;
        size_t g = (size_t)(n * TDEPTH + t) * PADW + p;
        s_j[t][p] = fjp[g];
        s_v[t][p] = fvp[g];
    }
    __syncthreads();

    // phase 1: sel -> sparsemoid, one thread per (t,d); es chunk-partials summed inline
    if (tid < TDEPTH * DD) {
        int t = tid >> 5, d = tid & 31;
        const float* xb = out + (size_t)b * OUT_STRIDE;
        float acc = 0.f;
        int c8 = (s_cnt[t] + 7) & ~7;
        for (int p = 0; p < c8; p += 8) {
            #pragma unroll
            for (int q = 0; q < 8; ++q)
                acc += xb[s_j[t][p + q] * 32 + d] * s_v[t][p + q];
        }
        float esv = 0.f;
        #pragma unroll
        for (int c = 0; c < 5; ++c)
            if (c < nch) esv += partL[((size_t)(n * TDEPTH + t) * 5 + c) * 32 + d];
        float sel = acc * esv;
        float tlv = (sel - s_thr[t]) * s_elt[t];
        sb[t][d] = fminf(fmaxf(0.5f * tlv + 0.5f, 0.f), 1.f);
    }
    __syncthreads();

    // phase 2: 64-leaf product x resp; threads = (cc 0..7) x (d 0..31)
    {
        int cc = tid >> 5, d = tid & 31;
        float sv0 = sb[0][d], sv1 = sb[1][d], sv2 = sb[2][d];
        float sv3 = sb[3][d], sv4 = sb[4][d], sv5 = sb[5][d];
        const float4* rp = (const float4*)(resp + ((size_t)n * DD + d) * 64 + cc * 8);
        float4 r0 = rp[0], r1 = rp[1];
        float rr[8] = {r0.x, r0.y, r0.z, r0.w, r1.x, r1.y, r1.z, r1.w};
        float partial = 0.f;
        #pragma unroll
        for (int c2 = 0; c2 < 8; ++c2) {
            int c = cc * 8 + c2;
            float p = ((c >> 0) & 1) ? (1.f - sv0) : sv0;
            p *= ((c >> 1) & 1) ? (1.f - sv1) : sv1;
            p *= ((c >> 2) & 1) ? (1.f - sv2) : sv2;
            p *= ((c >> 3) & 1) ? (1.f - sv3) : sv3;
            p *= ((c >> 4) & 1) ? (1.f - sv4) : sv4;
            p *= ((c >> 5) & 1) ? (1.f - sv5) : sv5;
            partial += p * rr[c2];
        }
        red[cc][d] = partial;
    }
    __syncthreads();
    if (tid < DD) {
        float s = 0.f;
        #pragma unroll
        for (int g = 0; g < 8; ++g) s += red[g][tid];
        out[(size_t)b * OUT_STRIDE + (size_t)(colOff + n) * DD + tid] = s;
    }
}

// ----------------------------------------------------------------
extern "C" void kernel_launch(void* const* d_in, const int* in_sizes, int n_in,
                              void* d_out, int out_size, void* d_ws, size_t ws_size,
                              hipStream_t stream) {
    const float* x = (const float*)d_in[0];
    float* out = (float*)d_out;

    // workspace layout
    const size_t NPAD = (size_t)3 * NT * PADW;   // 147456
    char* ws = (char*)d_ws;
    int*   fjp  = (int*)(ws);
    float* fvp  = (float*)(ws + NPAD * 4);
    int*   fcnt = (int*)(ws + 2 * NPAD * 4);
    float* part = (float*)(ws + 2 * NPAD * 4 + 16384);   // [3*NT][5][32]

    copy_x_kernel<<<(BB * 64 * DD + 255) / 256, 256, 0, stream>>>(x, out);

    fs_kernel<<<(3 * NT) / 4, 256, 0, stream>>>(
        (const float*)d_in[1], (const float*)d_in[6], (const float*)d_in[11],
        fjp, fvp, fcnt);

    es_kernel<<<dim3(NT, 9), 256, 0, stream>>>(
        (const float*)d_in[2], (const float*)d_in[7], (const float*)d_in[12], part);

    const int nchs[3] = {1, 3, 5};
    int colOff = 64;
    for (int L = 0; L < 3; ++L) {
        const float* thr  = (const float*)d_in[3 + 5 * L];
        const float* lt   = (const float*)d_in[4 + 5 * L];
        const float* resp = (const float*)d_in[5 + 5 * L];
        main_kernel<<<dim3(NTREES, BB), 256, 0, stream>>>(
            fjp + (size_t)L * NT * PADW, fvp + (size_t)L * NT * PADW,
            fcnt + L * NT, part + (size_t)L * NT * 5 * 32, nchs[L],
            thr, lt, resp, out, colOff);
        colOff += NTREES;
    }
}

// Round 6
// 87.460 us; speedup vs baseline: 3.1358x; 1.2610x over previous
//
#include <hip/hip_runtime.h>

#define OUT_COLS 448
#define OUT_STRIDE (OUT_COLS * 32)   // 14336 floats per batch row
#define NTREES 128
#define TDEPTH 6
#define NT (NTREES * TDEPTH)         // 768 rows per layer
#define DD 32
#define BB 64
#define PADW 64                      // padded compacted width for fs output

// DPP mov helper (compile-time ctrl)
template <int CTRL, int RMASK = 0xf, bool BC = true>
__device__ __forceinline__ float dppf(float v) {
    return __int_as_float(
        __builtin_amdgcn_update_dpp(0, __float_as_int(v), CTRL, RMASK, 0xf, BC));
}

// full-wave (64-lane) sum, result broadcast to all lanes via readlane
__device__ __forceinline__ float wred64(float x) {
    x += dppf<0x111>(x);   // row_shr:1
    x += dppf<0x112>(x);   // row_shr:2
    x += dppf<0x114>(x);   // row_shr:4
    x += dppf<0x118>(x);   // row_shr:8   -> per-16 inclusive
    x += __int_as_float(__builtin_amdgcn_update_dpp(0, __float_as_int(x), 0x142, 0xa, 0xf, false)); // row_bcast15
    x += __int_as_float(__builtin_amdgcn_update_dpp(0, __float_as_int(x), 0x143, 0xc, 0xf, false)); // row_bcast31
    return __int_as_float(__builtin_amdgcn_readlane(__float_as_int(x), 63));
}

// ---------------------------------------------------------------- copy x into out[:, 0:64, :]
__global__ void copy_x_kernel(const float* __restrict__ x, float* __restrict__ out) {
    int idx = blockIdx.x * blockDim.x + threadIdx.x;
    if (idx < BB * 64 * DD) {
        int b = idx >> 11;
        int r = idx & 2047;
        out[(size_t)b * OUT_STRIDE + r] = x[idx];
    }
}

// ---------------------------------------------------------------- fs sparsemax via Michelot
// One wave per row. Fixpoint: tau=(S-1)/k over shrinking active set {z>tau}.
template <int J>
__device__ __forceinline__ void fs_row(const float* __restrict__ zr, int lane,
                                       int* __restrict__ fj, float* __restrict__ fv,
                                       int* __restrict__ fcnt_p) {
    constexpr int T = J / 64;
    float z[T];
    #pragma unroll
    for (int t = 0; t < T; ++t) z[t] = zr[t * 64 + lane];
    float sp = 0.f;
    #pragma unroll
    for (int t = 0; t < T; ++t) sp += z[t];
    float k = (float)J;
    float tau = (wred64(sp) - 1.f) / k;
    #pragma unroll 1
    for (int it = 0; it < 64; ++it) {
        float s2 = 0.f, c2 = 0.f;
        #pragma unroll
        for (int t = 0; t < T; ++t) {
            bool g = z[t] > tau;
            s2 += g ? z[t] : 0.f;
            c2 += g ? 1.f : 0.f;
        }
        float S2 = wred64(s2);
        float K2 = wred64(c2);
        if (K2 == k) break;            // active set stopped shrinking -> fixpoint
        k = K2;
        tau = (S2 - 1.f) / K2;
    }
    // ballot/popcount compaction (order-free: main only does dot products)
    unsigned long long below = (1ull << lane) - 1ull;
    int base = 0;
    #pragma unroll
    for (int t = 0; t < T; ++t) {
        bool sup = z[t] > tau;
        unsigned long long m = __ballot(sup);
        int pos = base + __popcll(m & below);
        if (sup && pos < PADW) { fj[pos] = t * 64 + lane; fv[pos] = z[t] - tau; }
        base += __popcll(m);
    }
    int cnt = base < PADW ? base : PADW;
    for (int i = cnt + lane; i < PADW; i += 64) { fj[i] = 0; fv[i] = 0.f; }
    if (lane == 0) *fcnt_p = cnt;
}

__global__ __launch_bounds__(256)
void fs_kernel(const float* __restrict__ f0, const float* __restrict__ f1,
               const float* __restrict__ f2,
               int* __restrict__ fjp, float* __restrict__ fvp, int* __restrict__ fcnt) {
    int w = blockIdx.x * 4 + (threadIdx.x >> 6);   // 0..2303
    int lane = threadIdx.x & 63;
    if (w < NT) {
        fs_row<64>(f0 + (size_t)w * 64, lane,
                   fjp + (size_t)w * PADW, fvp + (size_t)w * PADW, fcnt + w);
    } else if (w < 2 * NT) {
        int r = w - NT;
        fs_row<192>(f1 + (size_t)r * 192, lane,
                    fjp + ((size_t)(NT + r)) * PADW, fvp + ((size_t)(NT + r)) * PADW,
                    fcnt + NT + r);
    } else {
        int r = w - 2 * NT;
        fs_row<320>(f2 + (size_t)r * 320, lane,
                    fjp + ((size_t)(2 * NT + r)) * PADW, fvp + ((size_t)(2 * NT + r)) * PADW,
                    fcnt + 2 * NT + r);
    }
}

// ---------------------------------------------------------------- es: lane-holds-row Michelot
// butterfly exchange step S (xor 1<<S within 32 lanes)
template <int S>
__device__ __forceinline__ void bstep(float* a, int lane) {
    constexpr int half = 16 >> S;
    bool up = ((lane >> S) & 1) != 0;
    #pragma unroll
    for (int q = 0; q < half; ++q) {
        float send = up ? a[q] : a[half + q];
        float recv;
        if constexpr (S == 0)      recv = dppf<0xB1>(send);
        else if constexpr (S == 1) recv = dppf<0x4E>(send);
        else recv = __int_as_float(__builtin_amdgcn_ds_swizzle(
                        __float_as_int(send), ((1 << S) << 10) | 0x1F));
        float keep = up ? a[half + q] : a[q];
        a[q] = keep + recv;
    }
}

// One wave handles one (row, chunk-of-64-j): lane = j. Row of 32 d's lives in 32 VGPRs.
__global__ __launch_bounds__(256)
void es_kernel(const float* __restrict__ e0, const float* __restrict__ e1,
               const float* __restrict__ e2, float* __restrict__ part) {
    int wid = blockIdx.x * 4 + (threadIdx.x >> 6);   // 0..6911
    int lane = threadIdx.x & 63;
    const float* esl; int row, chunk, J; size_t grow;
    if (wid < NT)            { esl = e0; row = wid; chunk = 0; J = 64; grow = (size_t)row; }
    else if (wid < 4 * NT)   { int q = wid - NT; esl = e1; row = q / 3; chunk = q - row * 3; J = 192; grow = (size_t)(NT + row); }
    else                     { int q = wid - 4 * NT; esl = e2; row = q / 5; chunk = q - row * 5; J = 320; grow = (size_t)(2 * NT + row); }

    const float4* zp4 = (const float4*)(esl + ((size_t)row * J + chunk * 64 + lane) * 32);
    float z[32];
    #pragma unroll
    for (int i = 0; i < 8; ++i) {
        float4 v = zp4[i];
        z[4 * i]     = v.x; z[4 * i + 1] = v.y;
        z[4 * i + 2] = v.z; z[4 * i + 3] = v.w;
    }
    // warm start: tau0 = max(z) - 1  (valid: tau* >= max-1 since (max-tau*)+ <= 1)
    float m0 = fmaxf(fmaxf(z[0], z[1]), z[2]);
    float m1 = fmaxf(fmaxf(z[3], z[4]), z[5]);
    float m2 = fmaxf(fmaxf(z[6], z[7]), z[8]);
    float m3 = fmaxf(fmaxf(z[9], z[10]), z[11]);
    float m4 = fmaxf(fmaxf(z[12], z[13]), z[14]);
    float m5 = fmaxf(fmaxf(z[15], z[16]), z[17]);
    float m6 = fmaxf(fmaxf(z[18], z[19]), z[20]);
    float m7 = fmaxf(fmaxf(z[21], z[22]), z[23]);
    float m8 = fmaxf(fmaxf(z[24], z[25]), z[26]);
    float m9 = fmaxf(fmaxf(z[27], z[28]), z[29]);
    float ma = fmaxf(z[30], z[31]);
    m0 = fmaxf(fmaxf(m0, m1), m2); m3 = fmaxf(fmaxf(m3, m4), m5);
    m6 = fmaxf(fmaxf(m6, m7), m8); m9 = fmaxf(m9, ma);
    float mx = fmaxf(fmaxf(m0, m3), fmaxf(m6, m9));

    float tau = mx - 1.0f;
    int kprev = -1;
    #pragma unroll 1
    for (int it = 0; it < 40; ++it) {
        float s0 = 0.f, s1 = 0.f, s2 = 0.f, s3 = 0.f;
        int k0 = 0, k1 = 0, k2 = 0, k3 = 0;
        #pragma unroll
        for (int i = 0; i < 8; ++i) {
            bool g0 = z[4 * i]     > tau; s0 += g0 ? z[4 * i]     : 0.f; k0 += g0;
            bool g1 = z[4 * i + 1] > tau; s1 += g1 ? z[4 * i + 1] : 0.f; k1 += g1;
            bool g2 = z[4 * i + 2] > tau; s2 += g2 ? z[4 * i + 2] : 0.f; k2 += g2;
            bool g3 = z[4 * i + 3] > tau; s3 += g3 ? z[4 * i + 3] : 0.f; k3 += g3;
        }
        float S = (s0 + s1) + (s2 + s3);
        int k = (k0 + k1) + (k2 + k3);
        bool chg = (k != kprev);
        kprev = k;
        tau = (S - 1.0f) / (float)k;   // idempotent once converged
        if (__ballot(chg) == 0ull) break;
    }
    // per-element sparsemax values, then butterfly transpose-reduce over the wave's 64 j's
    #pragma unroll
    for (int i = 0; i < 32; ++i) z[i] = fmaxf(z[i] - tau, 0.f);
    bstep<0>(z, lane);
    bstep<1>(z, lane);
    bstep<2>(z, lane);
    bstep<3>(z, lane);
    bstep<4>(z, lane);
    z[0] += __shfl_xor(z[0], 32, 64);
    // lane l holds sum over 64 j's for d = bitrev5(l&31)
    if (lane < 32) {
        int d = ((lane & 1) << 4) | ((lane & 2) << 2) | (lane & 4)
              | ((lane & 8) >> 2) | ((lane & 16) >> 4);
        part[(grow * 5 + chunk) * 32 + d] = z[0];
    }
}

// ---------------------------------------------------------------- fused per-(b,n) tree evaluation
__global__ __launch_bounds__(256)
void main_kernel(const int* __restrict__ fjp, const float* __restrict__ fvp,
                 const int* __restrict__ fcnt, const float* __restrict__ partL, int nch,
                 const float* __restrict__ thr, const float* __restrict__ lt,
                 const float* __restrict__ resp,
                 float* __restrict__ out, int colOff) {
    int n = blockIdx.x;
    int b = blockIdx.y;
    int tid = threadIdx.x;
    __shared__ int   s_j[TDEPTH][PADW];
    __shared__ float s_v[TDEPTH][PADW];
    __shared__ int   s_cnt[TDEPTH];
    __shared__ float s_thr[TDEPTH], s_elt[TDEPTH];
    __shared__ float sb[TDEPTH][DD];
    __shared__ float red[8][DD];

    if (tid < TDEPTH) {
        int r = n * TDEPTH + tid;
        s_cnt[tid] = fcnt[r];
        s_thr[tid] = thr[r];
        s_elt[tid] = expf(-lt[r]);
    }
    for (int i = tid; i < TDEPTH * PADW; i += 256) {
        int t = i >> 6, p = i & 63;
        size_t g = (size_t)(n * TDEPTH + t) * PADW + p;
        s_j[t][p] = fjp[g];
        s_v[t][p] = fvp[g];
    }
    __syncthreads();

    // phase 1: sel -> sparsemoid, one thread per (t,d); 16-deep gather for latency
    if (tid < TDEPTH * DD) {
        int t = tid >> 5, d = tid & 31;
        const float* xb = out + (size_t)b * OUT_STRIDE;
        float acc = 0.f;
        int c16 = (s_cnt[t] + 15) & ~15;
        for (int p = 0; p < c16; p += 16) {
            int jj[16]; float vv[16];
            #pragma unroll
            for (int q = 0; q < 16; ++q) { jj[q] = s_j[t][p + q]; vv[q] = s_v[t][p + q]; }
            #pragma unroll
            for (int q = 0; q < 16; ++q) acc += xb[jj[q] * 32 + d] * vv[q];
        }
        float esv = 0.f;
        #pragma unroll
        for (int c = 0; c < 5; ++c)
            if (c < nch) esv += partL[((size_t)(n * TDEPTH + t) * 5 + c) * 32 + d];
        float sel = acc * esv;
        float tlv = (sel - s_thr[t]) * s_elt[t];
        sb[t][d] = fminf(fmaxf(0.5f * tlv + 0.5f, 0.f), 1.f);
    }
    __syncthreads();

    // phase 2: 64-leaf product x resp; threads = (cc 0..7) x (d 0..31)
    {
        int cc = tid >> 5, d = tid & 31;
        float sv0 = sb[0][d], sv1 = sb[1][d], sv2 = sb[2][d];
        float sv3 = sb[3][d], sv4 = sb[4][d], sv5 = sb[5][d];
        const float4* rp = (const float4*)(resp + ((size_t)n * DD + d) * 64 + cc * 8);
        float4 r0 = rp[0], r1 = rp[1];
        float rr[8] = {r0.x, r0.y, r0.z, r0.w, r1.x, r1.y, r1.z, r1.w};
        float partial = 0.f;
        #pragma unroll
        for (int c2 = 0; c2 < 8; ++c2) {
            int c = cc * 8 + c2;
            float p = ((c >> 0) & 1) ? (1.f - sv0) : sv0;
            p *= ((c >> 1) & 1) ? (1.f - sv1) : sv1;
            p *= ((c >> 2) & 1) ? (1.f - sv2) : sv2;
            p *= ((c >> 3) & 1) ? (1.f - sv3) : sv3;
            p *= ((c >> 4) & 1) ? (1.f - sv4) : sv4;
            p *= ((c >> 5) & 1) ? (1.f - sv5) : sv5;
            partial += p * rr[c2];
        }
        red[cc][d] = partial;
    }
    __syncthreads();
    if (tid < DD) {
        float s = 0.f;
        #pragma unroll
        for (int g = 0; g < 8; ++g) s += red[g][tid];
        out[(size_t)b * OUT_STRIDE + (size_t)(colOff + n) * DD + tid] = s;
    }
}

// ----------------------------------------------------------------
extern "C" void kernel_launch(void* const* d_in, const int* in_sizes, int n_in,
                              void* d_out, int out_size, void* d_ws, size_t ws_size,
                              hipStream_t stream) {
    const float* x = (const float*)d_in[0];
    float* out = (float*)d_out;

    // workspace layout
    const size_t NPAD = (size_t)3 * NT * PADW;   // 147456
    char* ws = (char*)d_ws;
    int*   fjp  = (int*)(ws);
    float* fvp  = (float*)(ws + NPAD * 4);
    int*   fcnt = (int*)(ws + 2 * NPAD * 4);
    float* part = (float*)(ws + 2 * NPAD * 4 + 16384);   // [3*NT][5][32]

    copy_x_kernel<<<(BB * 64 * DD + 255) / 256, 256, 0, stream>>>(x, out);

    fs_kernel<<<(3 * NT) / 4, 256, 0, stream>>>(
        (const float*)d_in[1], (const float*)d_in[6], (const float*)d_in[11],
        fjp, fvp, fcnt);

    // 6912 wave-tasks (row x chunk x layer), 4 waves per block
    es_kernel<<<6912 / 4, 256, 0, stream>>>(
        (const float*)d_in[2], (const float*)d_in[7], (const float*)d_in[12], part);

    const int nchs[3] = {1, 3, 5};
    int colOff = 64;
    for (int L = 0; L < 3; ++L) {
        const float* thr  = (const float*)d_in[3 + 5 * L];
        const float* lt   = (const float*)d_in[4 + 5 * L];
        const float* resp = (const float*)d_in[5 + 5 * L];
        main_kernel<<<dim3(NTREES, BB), 256, 0, stream>>>(
            fjp + (size_t)L * NT * PADW, fvp + (size_t)L * NT * PADW,
            fcnt + L * NT, part + (size_t)L * NT * 5 * 32, nchs[L],
            thr, lt, resp, out, colOff);
        colOff += NTREES;
    }
}

// Round 7
// 58.293 us; speedup vs baseline: 4.7048x; 1.5004x over previous
//
#include <hip/hip_runtime.h>

#define OUT_COLS 448
#define OUT_STRIDE (OUT_COLS * 32)   // 14336 floats per batch row
#define NTREES 128
#define TDEPTH 6
#define NT (NTREES * TDEPTH)         // 768 rows per layer
#define DD 32
#define BB 64
#define PADW 64                      // padded compacted width for fs output

// DPP mov helper (compile-time ctrl)
template <int CTRL, int RMASK = 0xf, bool BC = true>
__device__ __forceinline__ float dppf(float v) {
    return __int_as_float(
        __builtin_amdgcn_update_dpp(0, __float_as_int(v), CTRL, RMASK, 0xf, BC));
}

// full-wave (64-lane) sum, result broadcast to all lanes via readlane
__device__ __forceinline__ float wred64(float x) {
    x += dppf<0x111>(x);
    x += dppf<0x112>(x);
    x += dppf<0x114>(x);
    x += dppf<0x118>(x);
    x += __int_as_float(__builtin_amdgcn_update_dpp(0, __float_as_int(x), 0x142, 0xa, 0xf, false)); // row_bcast15
    x += __int_as_float(__builtin_amdgcn_update_dpp(0, __float_as_int(x), 0x143, 0xc, 0xf, false)); // row_bcast31
    return __int_as_float(__builtin_amdgcn_readlane(__float_as_int(x), 63));
}

// ---------------------------------------------------------------- fs sparsemax via Michelot (one wave/row)
template <int J>
__device__ __forceinline__ void fs_row(const float* __restrict__ zr, int lane,
                                       int* __restrict__ fj, float* __restrict__ fv,
                                       int* __restrict__ fcnt_p) {
    constexpr int T = J / 64;
    float z[T];
    #pragma unroll
    for (int t = 0; t < T; ++t) z[t] = zr[t * 64 + lane];
    float sp = 0.f;
    #pragma unroll
    for (int t = 0; t < T; ++t) sp += z[t];
    float k = (float)J;
    float tau = (wred64(sp) - 1.f) / k;
    #pragma unroll 1
    for (int it = 0; it < 64; ++it) {
        float s2 = 0.f, c2 = 0.f;
        #pragma unroll
        for (int t = 0; t < T; ++t) {
            bool g = z[t] > tau;
            s2 += g ? z[t] : 0.f;
            c2 += g ? 1.f : 0.f;
        }
        float S2 = wred64(s2);
        float K2 = wred64(c2);
        if (K2 == k) break;
        k = K2;
        tau = (S2 - 1.f) / K2;
    }
    unsigned long long below = (1ull << lane) - 1ull;
    int base = 0;
    #pragma unroll
    for (int t = 0; t < T; ++t) {
        bool sup = z[t] > tau;
        unsigned long long m = __ballot(sup);
        int pos = base + __popcll(m & below);
        if (sup && pos < PADW) { fj[pos] = t * 64 + lane; fv[pos] = z[t] - tau; }
        base += __popcll(m);
    }
    int cnt = base < PADW ? base : PADW;
    for (int i = cnt + lane; i < PADW; i += 64) { fj[i] = 0; fv[i] = 0.f; }
    if (lane == 0) *fcnt_p = cnt;
}

// butterfly exchange step S (xor 1<<S within 32 lanes) for es transpose-reduce
template <int S>
__device__ __forceinline__ void bstep(float* a, int lane) {
    constexpr int half = 16 >> S;
    bool up = ((lane >> S) & 1) != 0;
    #pragma unroll
    for (int q = 0; q < half; ++q) {
        float send = up ? a[q] : a[half + q];
        float recv;
        if constexpr (S == 0)      recv = dppf<0xB1>(send);
        else if constexpr (S == 1) recv = dppf<0x4E>(send);
        else recv = __int_as_float(__builtin_amdgcn_ds_swizzle(
                        __float_as_int(send), ((1 << S) << 10) | 0x1F));
        float keep = up ? a[half + q] : a[q];
        a[q] = keep + recv;
    }
}

// ---------------------------------------------------------------- fused prep: copy_x + fs + es
// wave-task id:   [0,512)           copy x (float4)
//                 [512, 512+2304)   fs rows (3 layers)
//                 [2816, 2816+6912) es (row, chunk) tasks
__global__ __launch_bounds__(256)
void prep_kernel(const float* __restrict__ x,
                 const float* __restrict__ f0, const float* __restrict__ f1,
                 const float* __restrict__ f2,
                 const float* __restrict__ e0, const float* __restrict__ e1,
                 const float* __restrict__ e2,
                 int* __restrict__ fjp, float* __restrict__ fvp, int* __restrict__ fcnt,
                 float* __restrict__ part, float* __restrict__ out) {
    int w = blockIdx.x * 4 + (threadIdx.x >> 6);
    int lane = threadIdx.x & 63;

    if (w < 512) {                       // ---- copy x ----
        const float4* x4 = (const float4*)x;
        float4* o4 = (float4*)out;
        int g = w * 64 + lane;           // 0..32767
        int b = g >> 9, r = g & 511;     // 512 float4 per batch row region
        o4[(size_t)b * (OUT_STRIDE / 4) + r] = x4[g];
        return;
    }
    w -= 512;
    if (w < 3 * NT) {                    // ---- fs ----
        if (w < NT) {
            fs_row<64>(f0 + (size_t)w * 64, lane,
                       fjp + (size_t)w * PADW, fvp + (size_t)w * PADW, fcnt + w);
        } else if (w < 2 * NT) {
            int r = w - NT;
            fs_row<192>(f1 + (size_t)r * 192, lane,
                        fjp + (size_t)(NT + r) * PADW, fvp + (size_t)(NT + r) * PADW,
                        fcnt + NT + r);
        } else {
            int r = w - 2 * NT;
            fs_row<320>(f2 + (size_t)r * 320, lane,
                        fjp + (size_t)(2 * NT + r) * PADW, fvp + (size_t)(2 * NT + r) * PADW,
                        fcnt + 2 * NT + r);
        }
        return;
    }
    w -= 3 * NT;                         // ---- es: w in [0, 6912) ----
    const float* esl; int row, chunk, J; size_t grow;
    if (w < NT)          { esl = e0; row = w; chunk = 0; J = 64; grow = (size_t)row; }
    else if (w < 4 * NT) { int q = w - NT; esl = e1; row = q / 3; chunk = q - row * 3; J = 192; grow = (size_t)(NT + row); }
    else                 { int q = w - 4 * NT; esl = e2; row = q / 5; chunk = q - row * 5; J = 320; grow = (size_t)(2 * NT + row); }

    const float4* zp4 = (const float4*)(esl + ((size_t)row * J + chunk * 64 + lane) * 32);
    float z[32];
    #pragma unroll
    for (int i = 0; i < 8; ++i) {
        float4 v = zp4[i];
        z[4 * i] = v.x; z[4 * i + 1] = v.y; z[4 * i + 2] = v.z; z[4 * i + 3] = v.w;
    }
    float mx = z[0];
    #pragma unroll
    for (int i = 1; i < 32; ++i) mx = fmaxf(mx, z[i]);
    float tau = mx - 1.0f;               // warm start (valid lower bound on tau*)
    int kprev = -1;
    #pragma unroll 1
    for (int it = 0; it < 40; ++it) {
        float s0 = 0.f, s1 = 0.f, s2 = 0.f, s3 = 0.f;
        int k0 = 0, k1 = 0, k2 = 0, k3 = 0;
        #pragma unroll
        for (int i = 0; i < 8; ++i) {
            bool g0 = z[4 * i]     > tau; s0 += g0 ? z[4 * i]     : 0.f; k0 += g0;
            bool g1 = z[4 * i + 1] > tau; s1 += g1 ? z[4 * i + 1] : 0.f; k1 += g1;
            bool g2 = z[4 * i + 2] > tau; s2 += g2 ? z[4 * i + 2] : 0.f; k2 += g2;
            bool g3 = z[4 * i + 3] > tau; s3 += g3 ? z[4 * i + 3] : 0.f; k3 += g3;
        }
        float S = (s0 + s1) + (s2 + s3);
        int k = (k0 + k1) + (k2 + k3);
        bool chg = (k != kprev);
        kprev = k;
        tau = (S - 1.0f) / (float)k;
        if (__ballot(chg) == 0ull) break;
    }
    #pragma unroll
    for (int i = 0; i < 32; ++i) z[i] = fmaxf(z[i] - tau, 0.f);
    bstep<0>(z, lane);
    bstep<1>(z, lane);
    bstep<2>(z, lane);
    bstep<3>(z, lane);
    bstep<4>(z, lane);
    z[0] += __shfl_xor(z[0], 32, 64);
    if (lane < 32) {
        int d = ((lane & 1) << 4) | ((lane & 2) << 2) | (lane & 4)
              | ((lane & 8) >> 2) | ((lane & 16) >> 4);
        part[(grow * 5 + chunk) * 32 + d] = z[0];
    }
}

// ---------------------------------------------------------------- main: thread = (b,d), block = (n, 8 b's)
__global__ __launch_bounds__(256)
void main_kernel(const int* __restrict__ fjp, const float* __restrict__ fvp,
                 const int* __restrict__ fcnt, const float* __restrict__ partL, int nch,
                 const float* __restrict__ thr, const float* __restrict__ lt,
                 const float* __restrict__ resp,
                 float* __restrict__ out, int colOff) {
    int n = blockIdx.x;
    int tid = threadIdx.x;
    __shared__ int   s_j[TDEPTH][PADW];
    __shared__ float s_v[TDEPTH][PADW];
    __shared__ float s_resp[DD][65];     // padded: bank-conflict-free reads
    __shared__ float s_ess[TDEPTH][DD];
    __shared__ float s_thr[TDEPTH], s_elt[TDEPTH];
    __shared__ int   s_cnt[TDEPTH];

    for (int i = tid; i < TDEPTH * PADW; i += 256) {
        int t = i >> 6, p = i & 63;
        size_t g = (size_t)(n * TDEPTH + t) * PADW + p;
        s_j[t][p] = fjp[g];
        s_v[t][p] = fvp[g];
    }
    for (int i = tid; i < DD * 64; i += 256) {
        s_resp[i >> 6][i & 63] = resp[(size_t)n * (DD * 64) + i];
    }
    if (tid < TDEPTH * DD) {             // 192 threads: ess chunk-sum
        int t = tid >> 5, d = tid & 31;
        float e = 0.f;
        #pragma unroll
        for (int c = 0; c < 5; ++c)
            if (c < nch) e += partL[((size_t)(n * TDEPTH + t) * 5 + c) * 32 + d];
        s_ess[t][d] = e;
    }
    if (tid < TDEPTH) {
        int r = n * TDEPTH + tid;
        s_thr[tid] = thr[r];
        s_elt[tid] = expf(-lt[r]);
        s_cnt[tid] = fcnt[r];
    }
    __syncthreads();

    int b = blockIdx.y * 8 + (tid >> 5);   // 0..63
    int d = tid & 31;
    const float* xb = out + (size_t)b * OUT_STRIDE;

    float sv[TDEPTH];
    #pragma unroll
    for (int t = 0; t < TDEPTH; ++t) {
        float acc = 0.f;
        int c16 = (s_cnt[t] + 15) & ~15;
        for (int p = 0; p < c16; p += 16) {
            int jj[16]; float vv[16];
            #pragma unroll
            for (int q = 0; q < 16; ++q) { jj[q] = s_j[t][p + q]; vv[q] = s_v[t][p + q]; }
            #pragma unroll
            for (int q = 0; q < 16; ++q) acc += xb[jj[q] * 32 + d] * vv[q];
        }
        float sel = acc * s_ess[t][d];
        float tlv = (sel - s_thr[t]) * s_elt[t];
        sv[t] = fminf(fmaxf(0.5f * tlv + 0.5f, 0.f), 1.f);
    }

    // 64-leaf product via binary-tree factorization (126 mults), bit t of c selects (1-sv[t])
    float pr[64];
    pr[0] = sv[0];
    pr[1] = 1.f - sv[0];
    #pragma unroll
    for (int t = 1; t < TDEPTH; ++t) {
        const int len = 1 << t;
        float f1 = 1.f - sv[t];
        #pragma unroll
        for (int c = 0; c < 64; ++c) {   // static bounds; guard keeps indices compile-time
            if (c < len) {
                int cc = len - 1 - c;
                pr[cc + len] = pr[cc] * f1;
                pr[cc]       = pr[cc] * sv[t];
            }
        }
    }
    float o = 0.f;
    #pragma unroll
    for (int c = 0; c < 64; ++c) o += pr[c] * s_resp[d][c];
    out[(size_t)b * OUT_STRIDE + (size_t)(colOff + n) * DD + d] = o;
}

// ----------------------------------------------------------------
extern "C" void kernel_launch(void* const* d_in, const int* in_sizes, int n_in,
                              void* d_out, int out_size, void* d_ws, size_t ws_size,
                              hipStream_t stream) {
    const float* x = (const float*)d_in[0];
    float* out = (float*)d_out;

    const size_t NPAD = (size_t)3 * NT * PADW;   // 147456
    char* ws = (char*)d_ws;
    int*   fjp  = (int*)(ws);
    float* fvp  = (float*)(ws + NPAD * 4);
    int*   fcnt = (int*)(ws + 2 * NPAD * 4);
    float* part = (float*)(ws + 2 * NPAD * 4 + 16384);   // [3*NT][5][32]

    // 512 copy + 2304 fs + 6912 es = 9728 wave-tasks, 4 waves/block
    prep_kernel<<<9728 / 4, 256, 0, stream>>>(
        x,
        (const float*)d_in[1], (const float*)d_in[6], (const float*)d_in[11],
        (const float*)d_in[2], (const float*)d_in[7], (const float*)d_in[12],
        fjp, fvp, fcnt, part, out);

    const int nchs[3] = {1, 3, 5};
    int colOff = 64;
    for (int L = 0; L < 3; ++L) {
        const float* thr  = (const float*)d_in[3 + 5 * L];
        const float* lt   = (const float*)d_in[4 + 5 * L];
        const float* resp = (const float*)d_in[5 + 5 * L];
        main_kernel<<<dim3(NTREES, 8), 256, 0, stream>>>(
            fjp + (size_t)L * NT * PADW, fvp + (size_t)L * NT * PADW,
            fcnt + L * NT, part + (size_t)L * NT * 5 * 32, nchs[L],
            thr, lt, resp, out, colOff);
        colOff += NTREES;
    }
}